// Round 7
// baseline (131918.750 us; speedup 1.0000x reference)
//
#include <hip/hip_runtime.h>
#include <cstdint>
#include <cstddef>

// PlainRNN fused: h_{t+1} = tanh(h_t @ W_eff + b_eff), traj[t] = h_t @ W_h2o + b_h2o
// W_eff = W_h2h + W_h2o @ W_i2h  (recurrence composition removes x from the loop)
//
// Persistent kernel: 16 groups (16 batch rows) x 16 member blocks (72 of 1152 cols).
// Same-XCD groups by construction (HW_REG_XCC_ID + per-XCD slot counter).
//
// Cache model (explains R1..R6): atomics & agent-scope ops execute at the MALL
// (~900cyc RT); plain stores dirty the XCD-local L2 (~200cyc RT) where plain/sc0
// loads see them. R5/R6 barriers paid multiple MALL hops per step.
// R7: the WHOLE barrier lives in the local L2 —
//   arrival: plain (workgroup-relaxed) flag store (dirties local-L2 line, same
//            proven mechanism as the R5 h-data path)
//   poll:    wave 0 only, lanes 0..15 sc0 loads (L1-bypass -> local L2) + ballot,
//            s_sleep backoff, __syncthreads release. Zero MALL traffic per step.
//   h data:  plain stores -> local L2; plain loads + 4-slot hbuf rotation
//            (128KB/step streams through 32KB L1 => always fresh L2 hits). [R5]

#define BATCH  256
#define INPUT  128
#define HIDDEN 1024
#define OUTPUT 128
#define TSTEPS 512
#define NCAT   1152
#define NTILE  72
#define GROUPS 16
#define MEMB   16
#define NSLOT  4

// workspace layout (bytes)
#define WS_WFRAG 0u
#define WS_BEFF  2621440u
#define WS_HBUF  2629632u                 // 4 slots x 256x1024 f16
#define WS_BAR   4726784u
// bar[] u32: [g*32 + m] = step flag of member m of group g (128B line per group,
//            only ever touched by group g's XCD => stays dirty-resident in its L2)
//            [512 + xcc*32] per-XCD slot counters (one-time, device scope)
#define BAR_U32S 768

typedef _Float16 f16;
typedef _Float16 v8h __attribute__((ext_vector_type(8)));
typedef float    v4f __attribute__((ext_vector_type(4)));

__device__ __forceinline__ float fast_tanh(float x){
  float e = __expf(2.0f * x);
  return (e - 1.0f) / (e + 1.0f);
}

// ---- bias composition
__global__ void k_bias(const float* __restrict__ bi2h, const float* __restrict__ bh2h,
                       const float* __restrict__ bh2o, const float* __restrict__ Wi2h,
                       float* __restrict__ beff){
  int n = blockIdx.x*256 + threadIdx.x;
  if (n >= 1168) return;
  float v = 0.f;
  if (n < HIDDEN){
    v = bi2h[n] + bh2h[n];
    for (int j=0;j<INPUT;j++) v += bh2o[j]*Wi2h[j*HIDDEN + n];
  } else if (n < NCAT){
    v = bh2o[n - HIDDEN];
  }
  beff[n] = v;
}

// ---- h_1 = tanh(x0 @ W_i2h + b_i2h + b_h2h) -> slot 0
__global__ void k_h1(const float* __restrict__ x0, const float* __restrict__ Wi2h,
                     const float* __restrict__ bi2h, const float* __restrict__ bh2h,
                     f16* __restrict__ hbuf){
  int idx = blockIdx.x*256 + threadIdx.x;
  int m = idx >> 10, n = idx & 1023;
  float acc = bi2h[n] + bh2h[n];
  const float* xr = x0 + m*INPUT;
  for (int j=0;j<INPUT;j++) acc += xr[j]*Wi2h[j*HIDDEN + n];
  hbuf[idx] = (f16)fast_tanh(acc);
}

// ---- traj[0] = x_0
__global__ void k_copy0(const float* __restrict__ x0, float* __restrict__ out){
  int i = blockIdx.x*256 + threadIdx.x;
  out[i] = x0[i];
}

// ---- W fragment packing: [mem 16][wave 4][kk 8][c 5][lane 64][8 halves]
__global__ void k_wfrag(const float* __restrict__ Wh2h, const float* __restrict__ Wh2o,
                        const float* __restrict__ Wi2h, f16* __restrict__ Wfrag){
  int gid = blockIdx.x*256 + threadIdx.x;
  int lane = gid & 63;
  int fi = gid >> 6;
  int c = fi % 5, kk = (fi/5) & 7, wv = (fi/40) & 3, mem = fi/160;
  int k0 = wv*256 + kk*32 + (lane>>4)*8;
  int n  = mem*NTILE + c*16 + (lane & 15);
  f16 vals[8];
  if (n >= NCAT){
    #pragma unroll
    for (int j=0;j<8;j++) vals[j] = (f16)0.f;
  } else if (n >= HIDDEN){
    #pragma unroll
    for (int j=0;j<8;j++) vals[j] = (f16)Wh2o[(k0+j)*OUTPUT + (n-HIDDEN)];
  } else {
    float acc[8];
    #pragma unroll
    for (int j=0;j<8;j++) acc[j] = Wh2h[(k0+j)*HIDDEN + n];
    for (int q=0;q<INPUT;q++){
      float wi = Wi2h[q*HIDDEN + n];
      #pragma unroll
      for (int j=0;j<8;j++) acc[j] += Wh2o[(k0+j)*OUTPUT + q]*wi;
    }
    #pragma unroll
    for (int j=0;j<8;j++) vals[j] = (f16)acc[j];
  }
  v8h pack;
  #pragma unroll
  for (int j=0;j<8;j++) pack[j] = vals[j];
  *(v8h*)(Wfrag + (size_t)gid*8) = pack;
}

// sc0 load: bypass L1, read this XCD's L2 (where group-mates' plain stores land)
__device__ __forceinline__ unsigned flag_load_sc0(const unsigned* p){
  unsigned r;
  asm volatile("global_load_dword %0, %1, off sc0\n\ts_waitcnt vmcnt(0)"
               : "=&v"(r) : "v"(p) : "memory");
  return r;
}

// ---- persistent recurrence kernel: 256 blocks x 256 threads, 1 block/CU (96KB dyn LDS)
__global__ void __launch_bounds__(256, 1)
k_rnn(const f16* __restrict__ Wfrag, const float* __restrict__ beff,
      f16* __restrict__ hbuf, unsigned int* __restrict__ bar,
      float* __restrict__ out){
  extern __shared__ char lds_raw[];
  float*    red    = (float*)lds_raw;              // [(c*3+rank)][lane][4] f32, 15360 B
  unsigned* s_slot = (unsigned*)(lds_raw + 16384);

  const int tid  = threadIdx.x;
  const int lane = tid & 63;
  const int wv   = tid >> 6;

  // Dynamic same-XCD group formation: group shares one XCD L2 BY CONSTRUCTION.
  if (tid == 0){
    unsigned xcc;
    asm volatile("s_getreg_b32 %0, hwreg(HW_REG_XCC_ID)" : "=s"(xcc));
    xcc &= 7;
    unsigned slot = atomicAdd(&bar[512 + xcc*32], 1u);  // one-time, device-scope
    *s_slot = xcc*32 + (slot & 31u);
  }
  __syncthreads();
  const unsigned sid = *s_slot;
  const int g   = sid >> 4;
  const int mem = sid & 15;
  if (g >= GROUPS) return;
  const int m0   = g * 16;
  const int n0   = mem * NTILE;
  const int quad = lane >> 4;
  const int l15  = lane & 15;

  // B fragments resident in registers for the whole 511-step loop
  v8h bw[8][5];
  {
    const f16* wp = Wfrag + ((size_t)((mem*4 + wv)*40)*64 + lane)*8;
    #pragma unroll
    for (int kk=0;kk<8;kk++)
      #pragma unroll
      for (int c=0;c<5;c++)
        bw[kk][c] = *(const v8h*)(wp + (size_t)((kk*5+c)*64)*8);
  }

  const int kbase = wv*256;
  unsigned int* flags = bar + g*32;   // group's 128B flag line, local-L2 resident

  // hoisted epilogue constants: wave wv owns tile c=wv (full) and wave 0 also c=4 (l15<8)
  const int  colA   = n0 + wv*16 + l15;          // always < 1152
  const bool A_hid  = (colA < HIDDEN);
  const float biasA = beff[colA];
  const bool has4   = (wv == 0) && (l15 < 8);
  const int  col4   = n0 + 64 + l15;
  const bool hid4   = (col4 < HIDDEN);
  const float bias4 = has4 ? beff[col4] : 0.f;
  const size_t hoffA = (size_t)(m0 + quad*4)*HIDDEN + colA;
  const size_t yoffA = (size_t)(m0 + quad*4)*OUTPUT + (colA - HIDDEN);
  const size_t hoff4 = (size_t)(m0 + quad*4)*HIDDEN + col4;
  const size_t yoff4 = (size_t)(m0 + quad*4)*OUTPUT + (col4 - HIDDEN);

  for (int t=1; t<TSTEPS; ++t){
    const f16* hin  = hbuf + (size_t)((t-1)&(NSLOT-1))*(BATCH*HIDDEN);
    f16*       hout = hbuf + (size_t)(t&(NSLOT-1))*(BATCH*HIDDEN);

    // A fragments: plain vector loads; 4-slot rotation => L1 capacity-evicted,
    // always a fresh hit in the shared XCD L2. lane = A[m=lane&15][k=quad*8+j].
    v8h af[8];
    {
      const v8h* abase = (const v8h*)(hin + (size_t)(m0 + l15)*HIDDEN + kbase + quad*8);
      #pragma unroll
      for (int kk=0;kk<8;kk++)
        af[kk] = abase[kk*4];
    }

    v4f acc[5];
    #pragma unroll
    for (int c=0;c<5;c++){ v4f z = {0.f,0.f,0.f,0.f}; acc[c] = z; }

    #pragma unroll
    for (int kk=0;kk<8;kk++){
      #pragma unroll
      for (int c=0;c<5;c++)
        acc[c] = __builtin_amdgcn_mfma_f32_16x16x32_f16(af[kk], bw[kk][c], acc[c], 0,0,0);
    }

    // cross-wave K reduction via LDS. tile c owner = c&3.
    #pragma unroll
    for (int c=0;c<5;c++){
      int owner = c & 3;
      if (wv != owner){
        int rank = (wv > owner) ? wv-1 : wv;
        *(v4f*)(red + ((size_t)(c*3 + rank)*64 + lane)*4) = acc[c];
      }
    }
    __syncthreads();   // (1) red visible; also guards red reuse vs next iter

    // owner sums
    v4f sA = acc[wv];
    #pragma unroll
    for (int r=0;r<3;r++) sA += *(const v4f*)(red + ((size_t)(wv*3 + r)*64 + lane)*4);
    v4f s4 = acc[4];
    if (wv == 0){
      #pragma unroll
      for (int r=0;r<3;r++) s4 += *(const v4f*)(red + ((size_t)(4*3 + r)*64 + lane)*4);
    }

    // hidden stores (consumed by the group next step) — before the drain barrier
    if (A_hid){
      #pragma unroll
      for (int r=0;r<4;r++)
        hout[hoffA + (size_t)r*HIDDEN] = (f16)fast_tanh(sA[r] + biasA);  // C/D: col=l15,row=quad*4+r
    }
    if (has4 && hid4){
      #pragma unroll
      for (int r=0;r<4;r++)
        hout[hoff4 + (size_t)r*HIDDEN] = (f16)fast_tanh(s4[r] + bias4);
    }
    __syncthreads();   // (2) every wave drained vmcnt(0): h stores committed to local L2
    if (tid == 0){
      // arrival: PLAIN (workgroup-relaxed) store — dirties the flag line in the
      // LOCAL XCD L2, exactly the R5-proven producer->consumer store path.
      __hip_atomic_store(&flags[mem], (unsigned)t, __ATOMIC_RELAXED, __HIP_MEMORY_SCOPE_WORKGROUP);
    }

    // y stores (consumed by nobody) — overlap group-mates' arrivals
    if (!A_hid){
      float* op = out + (size_t)t*(BATCH*OUTPUT) + yoffA;
      #pragma unroll
      for (int r=0;r<4;r++) op[(size_t)r*OUTPUT] = sA[r] + biasA;
    }
    if (has4 && !hid4){
      float* op = out + (size_t)t*(BATCH*OUTPUT) + yoff4;
      #pragma unroll
      for (int r=0;r<4;r++) op[(size_t)r*OUTPUT] = s4[r] + bias4;
    }

    // wave-0-only poll: lanes 0..15 sc0-load the group's flag line from the LOCAL
    // L2 (~200cyc RT), ballot across 16, s_sleep backoff. Other waves wait at (3).
    if (wv == 0){
      unsigned tries = 0;
      for (;;){
        unsigned f = (lane < MEMB) ? flag_load_sc0(&flags[lane]) : (unsigned)t;
        unsigned long long b = __ballot(f >= (unsigned)t);
        if (b == ~0ull || ++tries >= 2048u) break;   // bounded: fail visibly, never hang
        __builtin_amdgcn_s_sleep(1);
      }
    }
    __syncthreads();   // (3) release: all waves enter step t+1 with flags seen
  }
}

extern "C" void kernel_launch(void* const* d_in, const int* in_sizes, int n_in,
                              void* d_out, int out_size, void* d_ws, size_t ws_size,
                              hipStream_t stream){
  const float* x0   = (const float*)d_in[0];
  const float* Wi2h = (const float*)d_in[1];
  const float* bi2h = (const float*)d_in[2];
  const float* Wh2h = (const float*)d_in[3];
  const float* bh2h = (const float*)d_in[4];
  const float* Wh2o = (const float*)d_in[5];
  const float* bh2o = (const float*)d_in[6];
  float* out = (float*)d_out;
  char* ws = (char*)d_ws;

  f16*          Wfrag = (f16*)(ws + WS_WFRAG);
  float*        beff  = (float*)(ws + WS_BEFF);
  f16*          hbuf  = (f16*)(ws + WS_HBUF);
  unsigned int* bar   = (unsigned int*)(ws + WS_BAR);

  hipMemsetAsync(bar, 0, BAR_U32S*sizeof(unsigned int), stream);
  k_bias <<<5,    256, 0, stream>>>(bi2h, bh2h, bh2o, Wi2h, beff);
  k_h1   <<<1024, 256, 0, stream>>>(x0, Wi2h, bi2h, bh2h, hbuf);
  k_copy0<<<128,  256, 0, stream>>>(x0, out);
  k_wfrag<<<640,  256, 0, stream>>>(Wh2h, Wh2o, Wi2h, Wfrag);

  // 96KB dynamic LDS forces 1 block/CU -> 256 blocks co-resident, 32 per XCD,
  // 1 wave/SIMD -> full VGPR budget for register-resident W fragments.
  hipFuncSetAttribute((const void*)k_rnn, hipFuncAttributeMaxDynamicSharedMemorySize, 98304);
  k_rnn<<<256, 256, 98304, stream>>>(Wfrag, beff, hbuf, bar, out);
}

// Round 8
// 1837.184 us; speedup vs baseline: 71.8049x; 71.8049x over previous
//
#include <hip/hip_runtime.h>
#include <cstdint>
#include <cstddef>

// PlainRNN fused: h_{t+1} = tanh(h_t @ W_eff + b_eff), traj[t] = h_t @ W_h2o + b_h2o
// W_eff = W_h2h + W_h2o @ W_i2h  (recurrence composition removes x from the loop)
//
// Persistent kernel: 16 groups (16 batch rows) x 16 member blocks (72 of 1152 cols).
// Same-XCD groups by construction (HW_REG_XCC_ID + per-XCD slot counter).
//
// PROVEN mechanisms (R1..R7):
//   data:    plain stores -> local L2; consumer plain loads at COLD addresses
//            (4-slot hbuf rotation evicts L1) — R5-proven.
//   barrier: agent-scope atomic store  <->  agent-scope atomic load ONLY.
//            Every sc0-poll variant froze (R4, R7). RMW arrivals serialize (R5).
//            All-wave polling hammers MALL (R6 regression).
// R8 barrier = best of each: agent atomic-store arrival (parallel, no RMW) +
// wave-0-only 15-lane coalesced agent-load ballot poll (immediate first poll,
// s_sleep backoff) + __syncthreads release. Member 15 (y-only cols) not gated on.

#define BATCH  256
#define INPUT  128
#define HIDDEN 1024
#define OUTPUT 128
#define TSTEPS 512
#define NCAT   1152
#define NTILE  72
#define GROUPS 16
#define MEMB   16
#define NSLOT  4

// workspace layout (bytes)
#define WS_WFRAG 0u
#define WS_BEFF  2621440u
#define WS_HBUF  2629632u                 // 4 slots x 256x1024 f16
#define WS_BAR   4726784u
// bar[] u32: [g*32 + m] = step flag of member m of group g (one 128B line per group)
//            [512 + xcc*32] per-XCD slot counters (one-time)
#define BAR_U32S 768

typedef _Float16 f16;
typedef _Float16 v8h __attribute__((ext_vector_type(8)));
typedef float    v4f __attribute__((ext_vector_type(4)));

__device__ __forceinline__ float fast_tanh(float x){
  float e = __expf(2.0f * x);
  return (e - 1.0f) / (e + 1.0f);
}

// ---- bias composition
__global__ void k_bias(const float* __restrict__ bi2h, const float* __restrict__ bh2h,
                       const float* __restrict__ bh2o, const float* __restrict__ Wi2h,
                       float* __restrict__ beff){
  int n = blockIdx.x*256 + threadIdx.x;
  if (n >= 1168) return;
  float v = 0.f;
  if (n < HIDDEN){
    v = bi2h[n] + bh2h[n];
    for (int j=0;j<INPUT;j++) v += bh2o[j]*Wi2h[j*HIDDEN + n];
  } else if (n < NCAT){
    v = bh2o[n - HIDDEN];
  }
  beff[n] = v;
}

// ---- h_1 = tanh(x0 @ W_i2h + b_i2h + b_h2h) -> slot 0
__global__ void k_h1(const float* __restrict__ x0, const float* __restrict__ Wi2h,
                     const float* __restrict__ bi2h, const float* __restrict__ bh2h,
                     f16* __restrict__ hbuf){
  int idx = blockIdx.x*256 + threadIdx.x;
  int m = idx >> 10, n = idx & 1023;
  float acc = bi2h[n] + bh2h[n];
  const float* xr = x0 + m*INPUT;
  for (int j=0;j<INPUT;j++) acc += xr[j]*Wi2h[j*HIDDEN + n];
  hbuf[idx] = (f16)fast_tanh(acc);
}

// ---- traj[0] = x_0
__global__ void k_copy0(const float* __restrict__ x0, float* __restrict__ out){
  int i = blockIdx.x*256 + threadIdx.x;
  out[i] = x0[i];
}

// ---- W fragment packing: [mem 16][wave 4][kk 8][c 5][lane 64][8 halves]
__global__ void k_wfrag(const float* __restrict__ Wh2h, const float* __restrict__ Wh2o,
                        const float* __restrict__ Wi2h, f16* __restrict__ Wfrag){
  int gid = blockIdx.x*256 + threadIdx.x;
  int lane = gid & 63;
  int fi = gid >> 6;
  int c = fi % 5, kk = (fi/5) & 7, wv = (fi/40) & 3, mem = fi/160;
  int k0 = wv*256 + kk*32 + (lane>>4)*8;
  int n  = mem*NTILE + c*16 + (lane & 15);
  f16 vals[8];
  if (n >= NCAT){
    #pragma unroll
    for (int j=0;j<8;j++) vals[j] = (f16)0.f;
  } else if (n >= HIDDEN){
    #pragma unroll
    for (int j=0;j<8;j++) vals[j] = (f16)Wh2o[(k0+j)*OUTPUT + (n-HIDDEN)];
  } else {
    float acc[8];
    #pragma unroll
    for (int j=0;j<8;j++) acc[j] = Wh2h[(k0+j)*HIDDEN + n];
    for (int q=0;q<INPUT;q++){
      float wi = Wi2h[q*HIDDEN + n];
      #pragma unroll
      for (int j=0;j<8;j++) acc[j] += Wh2o[(k0+j)*OUTPUT + q]*wi;
    }
    #pragma unroll
    for (int j=0;j<8;j++) vals[j] = (f16)acc[j];
  }
  v8h pack;
  #pragma unroll
  for (int j=0;j<8;j++) pack[j] = vals[j];
  *(v8h*)(Wfrag + (size_t)gid*8) = pack;
}

// ---- persistent recurrence kernel: 256 blocks x 256 threads, 1 block/CU (96KB dyn LDS)
__global__ void __launch_bounds__(256, 1)
k_rnn(const f16* __restrict__ Wfrag, const float* __restrict__ beff,
      f16* __restrict__ hbuf, unsigned int* __restrict__ bar,
      float* __restrict__ out){
  extern __shared__ char lds_raw[];
  float*    red    = (float*)lds_raw;              // [(c*3+rank)][lane][4] f32, 15360 B
  unsigned* s_slot = (unsigned*)(lds_raw + 16384);

  const int tid  = threadIdx.x;
  const int lane = tid & 63;
  const int wv   = tid >> 6;

  // Dynamic same-XCD group formation: group shares one XCD L2 BY CONSTRUCTION.
  if (tid == 0){
    unsigned xcc;
    asm volatile("s_getreg_b32 %0, hwreg(HW_REG_XCC_ID)" : "=s"(xcc));
    xcc &= 7;
    unsigned slot = atomicAdd(&bar[512 + xcc*32], 1u);  // one-time, device-scope
    *s_slot = xcc*32 + (slot & 31u);
  }
  __syncthreads();
  const unsigned sid = *s_slot;
  const int g   = sid >> 4;
  const int mem = sid & 15;
  if (g >= GROUPS) return;
  const int m0   = g * 16;
  const int n0   = mem * NTILE;
  const int quad = lane >> 4;
  const int l15  = lane & 15;

  // B fragments resident in registers for the whole 511-step loop
  v8h bw[8][5];
  {
    const f16* wp = Wfrag + ((size_t)((mem*4 + wv)*40)*64 + lane)*8;
    #pragma unroll
    for (int kk=0;kk<8;kk++)
      #pragma unroll
      for (int c=0;c<5;c++)
        bw[kk][c] = *(const v8h*)(wp + (size_t)((kk*5+c)*64)*8);
  }

  const int kbase = wv*256;
  unsigned int* flags = bar + g*32;   // one 128B line per group; [m] = member m's step

  // hoisted epilogue constants: wave wv owns tile c=wv (full) and wave 0 also c=4 (l15<8)
  const int  colA   = n0 + wv*16 + l15;          // always < 1152
  const bool A_hid  = (colA < HIDDEN);
  const float biasA = beff[colA];
  const bool has4   = (wv == 0) && (l15 < 8);
  const int  col4   = n0 + 64 + l15;
  const bool hid4   = (col4 < HIDDEN);
  const float bias4 = has4 ? beff[col4] : 0.f;
  const size_t hoffA = (size_t)(m0 + quad*4)*HIDDEN + colA;
  const size_t yoffA = (size_t)(m0 + quad*4)*OUTPUT + (colA - HIDDEN);
  const size_t hoff4 = (size_t)(m0 + quad*4)*HIDDEN + col4;
  const size_t yoff4 = (size_t)(m0 + quad*4)*OUTPUT + (col4 - HIDDEN);

  for (int t=1; t<TSTEPS; ++t){
    const f16* hin  = hbuf + (size_t)((t-1)&(NSLOT-1))*(BATCH*HIDDEN);
    f16*       hout = hbuf + (size_t)(t&(NSLOT-1))*(BATCH*HIDDEN);

    // A fragments: plain vector loads; 4-slot rotation => L1 capacity-evicted,
    // always a fresh hit in the shared XCD L2. lane = A[m=lane&15][k=quad*8+j].
    v8h af[8];
    {
      const v8h* abase = (const v8h*)(hin + (size_t)(m0 + l15)*HIDDEN + kbase + quad*8);
      #pragma unroll
      for (int kk=0;kk<8;kk++)
        af[kk] = abase[kk*4];
    }

    v4f acc[5];
    #pragma unroll
    for (int c=0;c<5;c++){ v4f z = {0.f,0.f,0.f,0.f}; acc[c] = z; }

    #pragma unroll
    for (int kk=0;kk<8;kk++){
      #pragma unroll
      for (int c=0;c<5;c++)
        acc[c] = __builtin_amdgcn_mfma_f32_16x16x32_f16(af[kk], bw[kk][c], acc[c], 0,0,0);
    }

    // cross-wave K reduction via LDS. tile c owner = c&3.
    #pragma unroll
    for (int c=0;c<5;c++){
      int owner = c & 3;
      if (wv != owner){
        int rank = (wv > owner) ? wv-1 : wv;
        *(v4f*)(red + ((size_t)(c*3 + rank)*64 + lane)*4) = acc[c];
      }
    }
    __syncthreads();   // (1) red visible; also guards red reuse vs next iter

    // owner sums
    v4f sA = acc[wv];
    #pragma unroll
    for (int r=0;r<3;r++) sA += *(const v4f*)(red + ((size_t)(wv*3 + r)*64 + lane)*4);
    v4f s4 = acc[4];
    if (wv == 0){
      #pragma unroll
      for (int r=0;r<3;r++) s4 += *(const v4f*)(red + ((size_t)(4*3 + r)*64 + lane)*4);
    }

    // hidden stores (consumed by the group next step) — before the drain barrier
    if (A_hid){
      #pragma unroll
      for (int r=0;r<4;r++)
        hout[hoffA + (size_t)r*HIDDEN] = (f16)fast_tanh(sA[r] + biasA);  // C/D: col=l15,row=quad*4+r
    }
    if (has4 && hid4){
      #pragma unroll
      for (int r=0;r<4;r++)
        hout[hoff4 + (size_t)r*HIDDEN] = (f16)fast_tanh(s4[r] + bias4);
    }
    __syncthreads();   // (2) every wave drained vmcnt(0): h stores committed to L2
    if (tid == 0 && mem < 15){
      // arrival: agent-scope atomic STORE (R6-proven visibility), no RMW
      // serialization — 15 members post concurrently. Member 15 is y-only:
      // nobody gates on it.
      __hip_atomic_store(&flags[mem], (unsigned)t, __ATOMIC_RELAXED, __HIP_MEMORY_SCOPE_AGENT);
    }

    // y stores (consumed by nobody) — overlap group-mates' arrivals
    if (!A_hid){
      float* op = out + (size_t)t*(BATCH*OUTPUT) + yoffA;
      #pragma unroll
      for (int r=0;r<4;r++) op[(size_t)r*OUTPUT] = sA[r] + biasA;
    }
    if (has4 && !hid4){
      float* op = out + (size_t)t*(BATCH*OUTPUT) + yoff4;
      #pragma unroll
      for (int r=0;r<4;r++) op[(size_t)r*OUTPUT] = s4[r] + bias4;
    }

    // wave-0-only ballot poll (R7 structure + R6-proven agent loads): lanes 0..14
    // read the group flag line in one coalesced MALL round trip. First poll
    // immediate; s_sleep backoff only on miss. Others wait at (3).
    if (wv == 0){
      unsigned tries = 0;
      for (;;){
        unsigned f = (lane < 15)
          ? __hip_atomic_load(&flags[lane], __ATOMIC_RELAXED, __HIP_MEMORY_SCOPE_AGENT)
          : (unsigned)t;
        unsigned long long b = __ballot(f >= (unsigned)t);
        if (b == ~0ull) break;
        if (++tries >= 4096u) break;      // bounded: fail visibly, never hang
        __builtin_amdgcn_s_sleep(1);
      }
    }
    __syncthreads();   // (3) release: all waves enter step t+1 with flags seen
  }
}

extern "C" void kernel_launch(void* const* d_in, const int* in_sizes, int n_in,
                              void* d_out, int out_size, void* d_ws, size_t ws_size,
                              hipStream_t stream){
  const float* x0   = (const float*)d_in[0];
  const float* Wi2h = (const float*)d_in[1];
  const float* bi2h = (const float*)d_in[2];
  const float* Wh2h = (const float*)d_in[3];
  const float* bh2h = (const float*)d_in[4];
  const float* Wh2o = (const float*)d_in[5];
  const float* bh2o = (const float*)d_in[6];
  float* out = (float*)d_out;
  char* ws = (char*)d_ws;

  f16*          Wfrag = (f16*)(ws + WS_WFRAG);
  float*        beff  = (float*)(ws + WS_BEFF);
  f16*          hbuf  = (f16*)(ws + WS_HBUF);
  unsigned int* bar   = (unsigned int*)(ws + WS_BAR);

  hipMemsetAsync(bar, 0, BAR_U32S*sizeof(unsigned int), stream);
  k_bias <<<5,    256, 0, stream>>>(bi2h, bh2h, bh2o, Wi2h, beff);
  k_h1   <<<1024, 256, 0, stream>>>(x0, Wi2h, bi2h, bh2h, hbuf);
  k_copy0<<<128,  256, 0, stream>>>(x0, out);
  k_wfrag<<<640,  256, 0, stream>>>(Wh2h, Wh2o, Wi2h, Wfrag);

  // 96KB dynamic LDS forces 1 block/CU -> 256 blocks co-resident, 32 per XCD,
  // 1 wave/SIMD -> full VGPR budget for register-resident W fragments.
  hipFuncSetAttribute((const void*)k_rnn, hipFuncAttributeMaxDynamicSharedMemorySize, 98304);
  k_rnn<<<256, 256, 98304, stream>>>(Wfrag, beff, hbuf, bar, out);
}